// Round 2
// baseline (504.129 us; speedup 1.0000x reference)
//
#include <hip/hip_runtime.h>

#define TB 262144

typedef short bf16x8 __attribute__((ext_vector_type(8)));
typedef float f32x4 __attribute__((ext_vector_type(4)));

__device__ __forceinline__ unsigned short f2bf(float f) {
  unsigned int u = __float_as_uint(f);
  unsigned int r = (u + 0x7fffu + ((u >> 16) & 1u)) >> 16;
  return (unsigned short)r;
}
__device__ __forceinline__ float sigmoid_f(float x) {
  return __builtin_amdgcn_rcpf(1.f + __expf(-x));
}
__device__ __forceinline__ float tanh_f(float x) {
  return 1.f - 2.f * __builtin_amdgcn_rcpf(__expf(2.f * x) + 1.f);
}

// Convert the 5 weight matrices to bf16 in workspace.
// Layout (ushort elems): [0,32768) w ; [32768,65536) wi ; [65536,98304) wf ;
//                        [98304,131072) wo ; [131072,147456) w_out
__global__ void wconv_kernel(const float* __restrict__ w, const float* __restrict__ wi,
                             const float* __restrict__ wf, const float* __restrict__ wo,
                             const float* __restrict__ wout, unsigned short* __restrict__ dst) {
  int i = blockIdx.x * 256 + threadIdx.x;
  float v;
  if (i < 32768) v = w[i];
  else if (i < 65536) v = wi[i - 32768];
  else if (i < 98304) v = wf[i - 65536];
  else if (i < 131072) v = wo[i - 98304];
  else v = wout[i - 131072];
  dst[i] = f2bf(v);
}

// 64 rows per block, 4 waves. Wave w owns gate-columns [32w, 32w+32).
__global__ __launch_bounds__(256, 4) void lstm_main(
    const float* __restrict__ c_prev, const float* __restrict__ h_prev,
    const float* __restrict__ x, const unsigned short* __restrict__ wbf,
    const float* __restrict__ b, const float* __restrict__ bi,
    const float* __restrict__ bf_, const float* __restrict__ bo,
    const float* __restrict__ b_out,
    float* __restrict__ out_c, float* __restrict__ out_h, float* __restrict__ out_y) {
  // LDS: phase 1: xh bf16 [64][256] swizzled (32 KB). phase 3 (aliased): h bf16 [64][128].
  __shared__ unsigned short smem[16384];
  const int tid = threadIdx.x;
  const int wave = tid >> 6;
  const int lane = tid & 63;
  const int lr = lane & 15;   // frag row/col
  const int lq = lane >> 4;   // quad
  const int row0 = blockIdx.x * 64;

  // ---- Phase 1: cooperative stage of xh -> LDS (bf16, XOR-swizzled) ----
  {
    const int tr = tid >> 5;         // 0..7
    const int tc = (tid & 31) * 4;   // 0..124
#pragma unroll
    for (int it = 0; it < 8; ++it) {
      const int r = it * 8 + tr;
      const float4 vx = *reinterpret_cast<const float4*>(&x[(size_t)(row0 + r) * 128 + tc]);
      const float4 vh = *reinterpret_cast<const float4*>(&h_prev[(size_t)(row0 + r) * 128 + tc]);
      ushort4 ux; ux.x = f2bf(vx.x); ux.y = f2bf(vx.y); ux.z = f2bf(vx.z); ux.w = f2bf(vx.w);
      ushort4 uh; uh.x = f2bf(vh.x); uh.y = f2bf(vh.y); uh.z = f2bf(vh.z); uh.w = f2bf(vh.w);
      const int sw = (r & 7) << 3;
      *reinterpret_cast<ushort4*>(&smem[(r * 256 + tc) ^ sw]) = ux;
      *reinterpret_cast<ushort4*>(&smem[(r * 256 + 128 + tc) ^ sw]) = uh;
    }
  }
  __syncthreads();

  // ---- Phase 2: GEMM1 (gates) + elementwise, per-wave j-columns [wave*32, wave*32+32) ----
  const int j0 = wave * 32;
  unsigned int hpk[2][4][2];  // packed bf16 h for GEMM2 staging

#pragma unroll
  for (int jc = 0; jc < 2; ++jc) {
    const int jcol = j0 + jc * 16 + lr;

    // T14-style prefetch: issue scattered c_prev loads before the K-loop so
    // their ~900 cy HBM latency hides under the MFMAs.
    float cpre[4][4];
#pragma unroll
    for (int rf = 0; rf < 4; ++rf) {
#pragma unroll
      for (int i = 0; i < 4; ++i) {
        const int grow = row0 + rf * 16 + lq * 4 + i;
        cpre[rf][i] = c_prev[(size_t)grow * 128 + jcol];
      }
    }
    const float bz_s = b[jcol];
    const float bi_s = bi[jcol];
    const float bf_s = bf_[jcol];
    const float bo_s = bo[jcol];

    f32x4 acc[4][4];
    const f32x4 zero = {0.f, 0.f, 0.f, 0.f};
#pragma unroll
    for (int rf = 0; rf < 4; ++rf) {
#pragma unroll
      for (int g = 0; g < 4; ++g) acc[rf][g] = zero;
    }

#pragma unroll 2
    for (int kk = 0; kk < 8; ++kk) {
      const int kb = kk * 32 + lq * 8;
      const int woff = jcol * 256 + kb;
      const bf16x8 bz8 = *reinterpret_cast<const bf16x8*>(&wbf[woff]);
      const bf16x8 bi8 = *reinterpret_cast<const bf16x8*>(&wbf[32768 + woff]);
      const bf16x8 bf8 = *reinterpret_cast<const bf16x8*>(&wbf[65536 + woff]);
      const bf16x8 bo8 = *reinterpret_cast<const bf16x8*>(&wbf[98304 + woff]);
#pragma unroll
      for (int rf = 0; rf < 4; ++rf) {
        const int r = rf * 16 + lr;
        const bf16x8 a8 =
            *reinterpret_cast<const bf16x8*>(&smem[(r * 256 + kb) ^ ((r & 7) << 3)]);
        acc[rf][0] = __builtin_amdgcn_mfma_f32_16x16x32_bf16(a8, bz8, acc[rf][0], 0, 0, 0);
        acc[rf][1] = __builtin_amdgcn_mfma_f32_16x16x32_bf16(a8, bi8, acc[rf][1], 0, 0, 0);
        acc[rf][2] = __builtin_amdgcn_mfma_f32_16x16x32_bf16(a8, bf8, acc[rf][2], 0, 0, 0);
        acc[rf][3] = __builtin_amdgcn_mfma_f32_16x16x32_bf16(a8, bo8, acc[rf][3], 0, 0, 0);
      }
    }

#pragma unroll
    for (int rf = 0; rf < 4; ++rf) {
#pragma unroll
      for (int i = 0; i < 4; ++i) {
        const int grow = row0 + rf * 16 + lq * 4 + i;
        const size_t gi = (size_t)grow * 128 + jcol;
        const float z  = tanh_f(acc[rf][0][i] + bz_s);
        const float zi = sigmoid_f(acc[rf][1][i] + bi_s);
        const float zf = sigmoid_f(acc[rf][2][i] + bf_s);
        const float zo = sigmoid_f(acc[rf][3][i] + bo_s);
        const float cv = zf * cpre[rf][i] + zi * z;
        const float hv = zo * tanh_f(cv);
        out_c[gi] = cv;
        out_h[gi] = hv;
        const unsigned int hb = (unsigned int)f2bf(hv);
        if (i & 1) hpk[jc][rf][i >> 1] |= hb << 16;
        else       hpk[jc][rf][i >> 1]  = hb;
      }
    }
  }

  // ---- Phase 3: stage h -> LDS (bf16 [64][128], swizzled), aliases xh buffer ----
  __syncthreads();
#pragma unroll
  for (int jc = 0; jc < 2; ++jc) {
    const int col = j0 + jc * 16 + lr;
#pragma unroll
    for (int rf = 0; rf < 4; ++rf) {
#pragma unroll
      for (int p = 0; p < 2; ++p) {
        const int r = rf * 16 + lq * 4 + p * 2;
        smem[(r * 128 + col) ^ ((r & 7) << 3)] =
            (unsigned short)(hpk[jc][rf][p] & 0xffffu);
        smem[((r + 1) * 128 + col) ^ (((r + 1) & 7) << 3)] =
            (unsigned short)(hpk[jc][rf][p] >> 16);
      }
    }
  }
  __syncthreads();

  // ---- Phase 4: GEMM2 (y = sigmoid(h @ w_out^T + b_out)), 16 rows per wave ----
  const int rb2 = wave * 16;
  bf16x8 a2[4];
#pragma unroll
  for (int ks = 0; ks < 4; ++ks) {
    const int r = rb2 + lr;
    const int k = ks * 32 + lq * 8;
    a2[ks] = *reinterpret_cast<const bf16x8*>(&smem[(r * 128 + k) ^ ((r & 7) << 3)]);
  }
#pragma unroll
  for (int jc2 = 0; jc2 < 8; ++jc2) {
    const int n = jc2 * 16 + lr;
    const f32x4 zero = {0.f, 0.f, 0.f, 0.f};
    f32x4 acc2 = zero;
#pragma unroll
    for (int ks = 0; ks < 4; ++ks) {
      const bf16x8 bw =
          *reinterpret_cast<const bf16x8*>(&wbf[131072 + n * 128 + ks * 32 + lq * 8]);
      acc2 = __builtin_amdgcn_mfma_f32_16x16x32_bf16(a2[ks], bw, acc2, 0, 0, 0);
    }
    const float by_s = b_out[n];
#pragma unroll
    for (int i = 0; i < 4; ++i) {
      const int grow = row0 + rb2 + lq * 4 + i;
      out_y[(size_t)grow * 128 + n] = sigmoid_f(acc2[i] + by_s);
    }
  }
}

extern "C" void kernel_launch(void* const* d_in, const int* in_sizes, int n_in,
                              void* d_out, int out_size, void* d_ws, size_t ws_size,
                              hipStream_t stream) {
  const float* c_    = (const float*)d_in[0];
  const float* h_    = (const float*)d_in[1];
  const float* x     = (const float*)d_in[2];
  const float* w     = (const float*)d_in[3];
  const float* wi    = (const float*)d_in[4];
  const float* wf    = (const float*)d_in[5];
  const float* wo    = (const float*)d_in[6];
  const float* wout  = (const float*)d_in[7];
  const float* b     = (const float*)d_in[8];
  const float* bi    = (const float*)d_in[9];
  const float* bf_   = (const float*)d_in[10];
  const float* bo    = (const float*)d_in[11];
  const float* b_out = (const float*)d_in[12];

  unsigned short* wbf = (unsigned short*)d_ws;  // 147456 ushorts = 288 KiB
  float* out_c = (float*)d_out;
  float* out_h = out_c + (size_t)TB * 128;
  float* out_y = out_h + (size_t)TB * 128;

  hipLaunchKernelGGL(wconv_kernel, dim3(576), dim3(256), 0, stream,
                     w, wi, wf, wo, wout, wbf);
  hipLaunchKernelGGL(lstm_main, dim3(4096), dim3(256), 0, stream,
                     c_, h_, x, wbf, b, bi, bf_, bo, b_out, out_c, out_h, out_y);
}

// Round 3
// 362.747 us; speedup vs baseline: 1.3898x; 1.3898x over previous
//
#include <hip/hip_runtime.h>

#define TB 262144

typedef short bf16x8 __attribute__((ext_vector_type(8)));
typedef float f32x4 __attribute__((ext_vector_type(4)));

__device__ __forceinline__ unsigned short f2bf(float f) {
  unsigned int u = __float_as_uint(f);
  unsigned int r = (u + 0x7fffu + ((u >> 16) & 1u)) >> 16;
  return (unsigned short)r;
}
__device__ __forceinline__ float bf2f(unsigned short u) {
  return __uint_as_float(((unsigned int)u) << 16);
}
__device__ __forceinline__ float sigmoid_f(float x) {
  return __builtin_amdgcn_rcpf(1.f + __expf(-x));
}
__device__ __forceinline__ float tanh_f(float x) {
  return 1.f - 2.f * __builtin_amdgcn_rcpf(__expf(2.f * x) + 1.f);
}

// Convert the 5 weight matrices to bf16 in workspace.
// Layout (ushort elems): [0,32768) w ; [32768,65536) wi ; [65536,98304) wf ;
//                        [98304,131072) wo ; [131072,147456) w_out
__global__ void wconv_kernel(const float* __restrict__ w, const float* __restrict__ wi,
                             const float* __restrict__ wf, const float* __restrict__ wo,
                             const float* __restrict__ wout, unsigned short* __restrict__ dst) {
  int i = blockIdx.x * 256 + threadIdx.x;
  float v;
  if (i < 32768) v = w[i];
  else if (i < 65536) v = wi[i - 32768];
  else if (i < 98304) v = wf[i - 65536];
  else if (i < 131072) v = wo[i - 98304];
  else v = wout[i - 131072];
  dst[i] = f2bf(v);
}

// 64 rows per block, 4 waves. Wave w owns gate-columns [32w, 32w+32).
// All global outputs staged through LDS -> fully coalesced f32x4 line stores.
__global__ __launch_bounds__(256, 3) void lstm_main(
    const float* __restrict__ c_prev, const float* __restrict__ h_prev,
    const float* __restrict__ x, const unsigned short* __restrict__ wbf,
    const float* __restrict__ b, const float* __restrict__ bi,
    const float* __restrict__ bf_, const float* __restrict__ bo,
    const float* __restrict__ b_out,
    float* __restrict__ out_c, float* __restrict__ out_h, float* __restrict__ out_y) {
  // LDS layout:
  //   A [0,32768):      phase1 xh bf16 [64][256] swizzled; then c f32 [64][128]; then y f32 [64][128]
  //   B [32768,49152):  h bf16 [64][128] swizzled (GEMM2 operand + out_h source)
  __shared__ __align__(16) char smem_raw[49152];
  unsigned short* us_xh = (unsigned short*)smem_raw;
  float* f_c = (float*)smem_raw;
  float* f_y = (float*)smem_raw;
  unsigned short* us_h = (unsigned short*)(smem_raw + 32768);

  const int tid = threadIdx.x;
  const int wave = tid >> 6;
  const int lane = tid & 63;
  const int lr = lane & 15;   // frag row/col
  const int lq = lane >> 4;   // quad
  const int row0 = blockIdx.x * 64;
  const int j0 = wave * 32;

  // ---- Phase A: stage xh -> LDS (bf16, XOR-swizzled) + upfront c_prev loads ----
  // c_prev: both jc halves adjacent -> full 128B line fetches, no L2-residency reliance.
  float cpre[2][4][4];
#pragma unroll
  for (int rf = 0; rf < 4; ++rf) {
#pragma unroll
    for (int i = 0; i < 4; ++i) {
      const size_t base = (size_t)(row0 + rf * 16 + lq * 4 + i) * 128 + j0 + lr;
      cpre[0][rf][i] = c_prev[base];
      cpre[1][rf][i] = c_prev[base + 16];
    }
  }
  {
    const int tr = tid >> 5;         // 0..7
    const int tc = (tid & 31) * 4;   // 0..124
#pragma unroll
    for (int it = 0; it < 8; ++it) {
      const int r = it * 8 + tr;
      const float4 vx = *reinterpret_cast<const float4*>(&x[(size_t)(row0 + r) * 128 + tc]);
      const float4 vh = *reinterpret_cast<const float4*>(&h_prev[(size_t)(row0 + r) * 128 + tc]);
      ushort4 ux; ux.x = f2bf(vx.x); ux.y = f2bf(vx.y); ux.z = f2bf(vx.z); ux.w = f2bf(vx.w);
      ushort4 uh; uh.x = f2bf(vh.x); uh.y = f2bf(vh.y); uh.z = f2bf(vh.z); uh.w = f2bf(vh.w);
      const int sw = (r & 7) << 3;
      *reinterpret_cast<ushort4*>(&us_xh[(r * 256 + tc) ^ sw]) = ux;
      *reinterpret_cast<ushort4*>(&us_xh[(r * 256 + 128 + tc) ^ sw]) = uh;
    }
  }
  __syncthreads();

  // ---- Phase B: GEMM1 (gates) + elementwise; results held in registers ----
  float cv[2][4][4];
  unsigned int hpk[2][4][2];  // packed bf16 h

#pragma unroll
  for (int jc = 0; jc < 2; ++jc) {
    const int jcol = j0 + jc * 16 + lr;
    const float bz_s = b[jcol];
    const float bi_s = bi[jcol];
    const float bf_s = bf_[jcol];
    const float bo_s = bo[jcol];

    f32x4 acc[4][4];
    const f32x4 zero = {0.f, 0.f, 0.f, 0.f};
#pragma unroll
    for (int rf = 0; rf < 4; ++rf) {
#pragma unroll
      for (int g = 0; g < 4; ++g) acc[rf][g] = zero;
    }

#pragma unroll 2
    for (int kk = 0; kk < 8; ++kk) {
      const int kb = kk * 32 + lq * 8;
      const int woff = jcol * 256 + kb;
      const bf16x8 bz8 = *reinterpret_cast<const bf16x8*>(&wbf[woff]);
      const bf16x8 bi8 = *reinterpret_cast<const bf16x8*>(&wbf[32768 + woff]);
      const bf16x8 bf8 = *reinterpret_cast<const bf16x8*>(&wbf[65536 + woff]);
      const bf16x8 bo8 = *reinterpret_cast<const bf16x8*>(&wbf[98304 + woff]);
#pragma unroll
      for (int rf = 0; rf < 4; ++rf) {
        const int r = rf * 16 + lr;
        const bf16x8 a8 =
            *reinterpret_cast<const bf16x8*>(&us_xh[(r * 256 + kb) ^ ((r & 7) << 3)]);
        acc[rf][0] = __builtin_amdgcn_mfma_f32_16x16x32_bf16(a8, bz8, acc[rf][0], 0, 0, 0);
        acc[rf][1] = __builtin_amdgcn_mfma_f32_16x16x32_bf16(a8, bi8, acc[rf][1], 0, 0, 0);
        acc[rf][2] = __builtin_amdgcn_mfma_f32_16x16x32_bf16(a8, bf8, acc[rf][2], 0, 0, 0);
        acc[rf][3] = __builtin_amdgcn_mfma_f32_16x16x32_bf16(a8, bo8, acc[rf][3], 0, 0, 0);
      }
    }

#pragma unroll
    for (int rf = 0; rf < 4; ++rf) {
#pragma unroll
      for (int i = 0; i < 4; ++i) {
        const float z  = tanh_f(acc[rf][0][i] + bz_s);
        const float zi = sigmoid_f(acc[rf][1][i] + bi_s);
        const float zf = sigmoid_f(acc[rf][2][i] + bf_s);
        const float zo = sigmoid_f(acc[rf][3][i] + bo_s);
        const float cvv = zf * cpre[jc][rf][i] + zi * z;
        const float hv = zo * tanh_f(cvv);
        cv[jc][rf][i] = cvv;
        const unsigned int hb = (unsigned int)f2bf(hv);
        if (i & 1) hpk[jc][rf][i >> 1] |= hb << 16;
        else       hpk[jc][rf][i >> 1]  = hb;
      }
    }
  }
  __syncthreads();  // xh in LDS A now dead

  // ---- Phase C: scatter c (f32) and h (bf16) into LDS ----
#pragma unroll
  for (int jc = 0; jc < 2; ++jc) {
    const int col = j0 + jc * 16 + lr;
#pragma unroll
    for (int rf = 0; rf < 4; ++rf) {
#pragma unroll
      for (int i = 0; i < 4; ++i) {
        const int r = rf * 16 + lq * 4 + i;
        f_c[r * 128 + col] = cv[jc][rf][i];
      }
#pragma unroll
      for (int p = 0; p < 2; ++p) {
        const int r = rf * 16 + lq * 4 + p * 2;
        us_h[(r * 128 + col) ^ ((r & 7) << 3)] =
            (unsigned short)(hpk[jc][rf][p] & 0xffffu);
        us_h[((r + 1) * 128 + col) ^ (((r + 1) & 7) << 3)] =
            (unsigned short)(hpk[jc][rf][p] >> 16);
      }
    }
  }
  __syncthreads();

  // ---- Phase D: coalesced c/h stores + GEMM2 compute ----
#pragma unroll
  for (int it = 0; it < 8; ++it) {
    const int chunk = it * 256 + tid;      // 0..2047
    const int r = chunk >> 5;              // 0..63
    const int c4 = (chunk & 31) * 4;       // 0..124
    const f32x4 v = *reinterpret_cast<const f32x4*>(&f_c[r * 128 + c4]);
    *reinterpret_cast<f32x4*>(&out_c[(size_t)(row0 + r) * 128 + c4]) = v;
  }
#pragma unroll
  for (int it = 0; it < 8; ++it) {
    const int chunk = it * 256 + tid;
    const int r = chunk >> 5;
    const int c4 = (chunk & 31) * 4;
    const ushort4 u = *reinterpret_cast<const ushort4*>(&us_h[(r * 128 + c4) ^ ((r & 7) << 3)]);
    f32x4 v;
    v.x = bf2f(u.x); v.y = bf2f(u.y); v.z = bf2f(u.z); v.w = bf2f(u.w);
    *reinterpret_cast<f32x4*>(&out_h[(size_t)(row0 + r) * 128 + c4]) = v;
  }

  // GEMM2: y = sigmoid(h @ w_out^T + b_out); wave owns 16 rows.
  const int rb2 = wave * 16;
  bf16x8 a2[4];
#pragma unroll
  for (int ks = 0; ks < 4; ++ks) {
    const int r = rb2 + lr;
    const int k = ks * 32 + lq * 8;
    a2[ks] = *reinterpret_cast<const bf16x8*>(&us_h[(r * 128 + k) ^ ((r & 7) << 3)]);
  }
  f32x4 yv[8];
#pragma unroll
  for (int jc2 = 0; jc2 < 8; ++jc2) {
    const int n = jc2 * 16 + lr;
    const f32x4 zero = {0.f, 0.f, 0.f, 0.f};
    f32x4 acc2 = zero;
#pragma unroll
    for (int ks = 0; ks < 4; ++ks) {
      const bf16x8 bw =
          *reinterpret_cast<const bf16x8*>(&wbf[131072 + n * 128 + ks * 32 + lq * 8]);
      acc2 = __builtin_amdgcn_mfma_f32_16x16x32_bf16(a2[ks], bw, acc2, 0, 0, 0);
    }
    const float by_s = b_out[n];
#pragma unroll
    for (int i = 0; i < 4; ++i) yv[jc2][i] = sigmoid_f(acc2[i] + by_s);
  }
  __syncthreads();  // LDS A (c) fully consumed

  // ---- Phase E: y -> LDS, then coalesced store ----
#pragma unroll
  for (int jc2 = 0; jc2 < 8; ++jc2) {
    const int n = jc2 * 16 + lr;
#pragma unroll
    for (int i = 0; i < 4; ++i) {
      const int r = rb2 + lq * 4 + i;
      f_y[r * 128 + n] = yv[jc2][i];
    }
  }
  __syncthreads();
#pragma unroll
  for (int it = 0; it < 8; ++it) {
    const int chunk = it * 256 + tid;
    const int r = chunk >> 5;
    const int c4 = (chunk & 31) * 4;
    const f32x4 v = *reinterpret_cast<const f32x4*>(&f_y[r * 128 + c4]);
    *reinterpret_cast<f32x4*>(&out_y[(size_t)(row0 + r) * 128 + c4]) = v;
  }
}

extern "C" void kernel_launch(void* const* d_in, const int* in_sizes, int n_in,
                              void* d_out, int out_size, void* d_ws, size_t ws_size,
                              hipStream_t stream) {
  const float* c_    = (const float*)d_in[0];
  const float* h_    = (const float*)d_in[1];
  const float* x     = (const float*)d_in[2];
  const float* w     = (const float*)d_in[3];
  const float* wi    = (const float*)d_in[4];
  const float* wf    = (const float*)d_in[5];
  const float* wo    = (const float*)d_in[6];
  const float* wout  = (const float*)d_in[7];
  const float* b     = (const float*)d_in[8];
  const float* bi    = (const float*)d_in[9];
  const float* bf_   = (const float*)d_in[10];
  const float* bo    = (const float*)d_in[11];
  const float* b_out = (const float*)d_in[12];

  unsigned short* wbf = (unsigned short*)d_ws;  // 147456 ushorts = 288 KiB
  float* out_c = (float*)d_out;
  float* out_h = out_c + (size_t)TB * 128;
  float* out_y = out_h + (size_t)TB * 128;

  hipLaunchKernelGGL(wconv_kernel, dim3(576), dim3(256), 0, stream,
                     w, wi, wf, wo, wout, wbf);
  hipLaunchKernelGGL(lstm_main, dim3(4096), dim3(256), 0, stream,
                     c_, h_, x, wbf, b, bi, bf_, bo, b_out, out_c, out_h, out_y);
}

// Round 4
// 317.799 us; speedup vs baseline: 1.5863x; 1.1414x over previous
//
#include <hip/hip_runtime.h>

#define TB 262144

typedef short bf16x8 __attribute__((ext_vector_type(8)));
typedef float f32x4 __attribute__((ext_vector_type(4)));

__device__ __forceinline__ unsigned short f2bf(float f) {
  unsigned int u = __float_as_uint(f);
  unsigned int r = (u + 0x7fffu + ((u >> 16) & 1u)) >> 16;
  return (unsigned short)r;
}
__device__ __forceinline__ float sigmoid_f(float x) {
  return __builtin_amdgcn_rcpf(1.f + __expf(-x));
}
__device__ __forceinline__ float tanh_f(float x) {
  return 1.f - 2.f * __builtin_amdgcn_rcpf(__expf(2.f * x) + 1.f);
}

// Convert the 5 weight matrices to bf16 in workspace.
// Layout (ushort elems): [0,32768) w ; [32768,65536) wi ; [65536,98304) wf ;
//                        [98304,131072) wo ; [131072,147456) w_out
__global__ void wconv_kernel(const float* __restrict__ w, const float* __restrict__ wi,
                             const float* __restrict__ wf, const float* __restrict__ wo,
                             const float* __restrict__ wout, unsigned short* __restrict__ dst) {
  int i = blockIdx.x * 256 + threadIdx.x;
  float v;
  if (i < 32768) v = w[i];
  else if (i < 65536) v = wi[i - 32768];
  else if (i < 98304) v = wf[i - 65536];
  else if (i < 131072) v = wo[i - 98304];
  else v = wout[i - 131072];
  dst[i] = f2bf(v);
}

// 64 rows/block, 4 waves; wave w owns c-columns [32w, 32w+32).
// jc-paired direct global stores assemble full 128B lines in L2 (no LDS
// staging of outputs -> low register pressure, no spills, 2 syncs total).
__global__ __launch_bounds__(256, 3) void lstm_main(
    const float* __restrict__ c_prev, const float* __restrict__ h_prev,
    const float* __restrict__ x, const unsigned short* __restrict__ wbf,
    const float* __restrict__ b, const float* __restrict__ bi,
    const float* __restrict__ bf_, const float* __restrict__ bo,
    const float* __restrict__ b_out,
    float* __restrict__ out_c, float* __restrict__ out_h, float* __restrict__ out_y) {
  __shared__ unsigned short us_xh[16384];  // 32 KB: xh bf16 [64][256], XOR-swizzled
  __shared__ unsigned short us_h[8192];    // 16 KB: h  bf16 [64][128], XOR-swizzled

  const int tid = threadIdx.x;
  const int wave = tid >> 6;
  const int lane = tid & 63;
  const int lr = lane & 15;   // frag row/col
  const int lq = lane >> 4;   // quad
  const int row0 = blockIdx.x * 64;
  const int j0 = wave * 32;

  // ---- Phase A: stage xh -> LDS (bf16, XOR-swizzled) ----
  {
    const int tr = tid >> 5;         // 0..7
    const int tc = (tid & 31) * 4;   // 0..124
#pragma unroll
    for (int it = 0; it < 8; ++it) {
      const int r = it * 8 + tr;
      const float4 vx = *reinterpret_cast<const float4*>(&x[(size_t)(row0 + r) * 128 + tc]);
      const float4 vh = *reinterpret_cast<const float4*>(&h_prev[(size_t)(row0 + r) * 128 + tc]);
      ushort4 ux; ux.x = f2bf(vx.x); ux.y = f2bf(vx.y); ux.z = f2bf(vx.z); ux.w = f2bf(vx.w);
      ushort4 uh; uh.x = f2bf(vh.x); uh.y = f2bf(vh.y); uh.z = f2bf(vh.z); uh.w = f2bf(vh.w);
      const int sw = (r & 7) << 3;
      *reinterpret_cast<ushort4*>(&us_xh[(r * 256 + tc) ^ sw]) = ux;
      *reinterpret_cast<ushort4*>(&us_xh[(r * 256 + 128 + tc) ^ sw]) = uh;
    }
  }
  __syncthreads();

  // ---- Phase B: GEMM1 + elementwise; jc=0 results held, jc=1 stores paired ----
  float cv0[4][4];
  float hv0[4][4];

#pragma unroll
  for (int jc = 0; jc < 2; ++jc) {
    const int jcol = j0 + jc * 16 + lr;

    // c_prev prefetch for this jc: issued before the K-loop, latency hides
    // under the MFMAs. jc=1 hits the L2 line fetched by jc=0 (same 128B line).
    float cpre[4][4];
#pragma unroll
    for (int rf = 0; rf < 4; ++rf) {
#pragma unroll
      for (int i = 0; i < 4; ++i) {
        cpre[rf][i] = c_prev[(size_t)(row0 + rf * 16 + lq * 4 + i) * 128 + jcol];
      }
    }
    const float bz_s = b[jcol];
    const float bi_s = bi[jcol];
    const float bf_s = bf_[jcol];
    const float bo_s = bo[jcol];

    f32x4 acc[4][4];
    const f32x4 zero = {0.f, 0.f, 0.f, 0.f};
#pragma unroll
    for (int rf = 0; rf < 4; ++rf) {
#pragma unroll
      for (int g = 0; g < 4; ++g) acc[rf][g] = zero;
    }

#pragma unroll 2
    for (int kk = 0; kk < 8; ++kk) {
      const int kb = kk * 32 + lq * 8;
      const int woff = jcol * 256 + kb;
      const bf16x8 bz8 = *reinterpret_cast<const bf16x8*>(&wbf[woff]);
      const bf16x8 bi8 = *reinterpret_cast<const bf16x8*>(&wbf[32768 + woff]);
      const bf16x8 bf8 = *reinterpret_cast<const bf16x8*>(&wbf[65536 + woff]);
      const bf16x8 bo8 = *reinterpret_cast<const bf16x8*>(&wbf[98304 + woff]);
#pragma unroll
      for (int rf = 0; rf < 4; ++rf) {
        const int r = rf * 16 + lr;
        const bf16x8 a8 =
            *reinterpret_cast<const bf16x8*>(&us_xh[(r * 256 + kb) ^ ((r & 7) << 3)]);
        acc[rf][0] = __builtin_amdgcn_mfma_f32_16x16x32_bf16(a8, bz8, acc[rf][0], 0, 0, 0);
        acc[rf][1] = __builtin_amdgcn_mfma_f32_16x16x32_bf16(a8, bi8, acc[rf][1], 0, 0, 0);
        acc[rf][2] = __builtin_amdgcn_mfma_f32_16x16x32_bf16(a8, bf8, acc[rf][2], 0, 0, 0);
        acc[rf][3] = __builtin_amdgcn_mfma_f32_16x16x32_bf16(a8, bo8, acc[rf][3], 0, 0, 0);
      }
    }

#pragma unroll
    for (int rf = 0; rf < 4; ++rf) {
#pragma unroll
      for (int i = 0; i < 4; ++i) {
        const int r = rf * 16 + lq * 4 + i;
        const float z  = tanh_f(acc[rf][0][i] + bz_s);
        const float zi = sigmoid_f(acc[rf][1][i] + bi_s);
        const float zf = sigmoid_f(acc[rf][2][i] + bf_s);
        const float zo = sigmoid_f(acc[rf][3][i] + bo_s);
        const float cvv = zf * cpre[rf][i] + zi * z;
        const float hvv = zo * tanh_f(cvv);
        // h (bf16) into LDS for GEMM2 operand — no sync needed until GEMM2 reads.
        us_h[(r * 128 + jcol) ^ ((r & 7) << 3)] = f2bf(hvv);
        if (jc == 0) {
          cv0[rf][i] = cvv;
          hv0[rf][i] = hvv;
        } else {
          // Paired stores: cols j0+lr and j0+16+lr are adjacent 64B sectors of
          // the same 128B line -> L2 write-combines to a full-line HBM write.
          const size_t gi = (size_t)(row0 + r) * 128 + j0 + lr;
          out_c[gi]      = cv0[rf][i];
          out_c[gi + 16] = cvv;
          out_h[gi]      = hv0[rf][i];
          out_h[gi + 16] = hvv;
        }
      }
    }
  }
  __syncthreads();

  // ---- Phase C: GEMM2 (y = sigmoid(h @ w_out^T + b_out)); wave owns 16 rows.
  // Col-pairs (t*32, t*32+16) computed together -> paired full-line y stores.
  const int rb2 = wave * 16;
  bf16x8 a2[4];
#pragma unroll
  for (int ks = 0; ks < 4; ++ks) {
    const int r = rb2 + lr;
    const int k = ks * 32 + lq * 8;
    a2[ks] = *reinterpret_cast<const bf16x8*>(&us_h[(r * 128 + k) ^ ((r & 7) << 3)]);
  }
#pragma unroll
  for (int t = 0; t < 4; ++t) {
    const int n0 = t * 32 + lr;
    const int n1 = n0 + 16;
    const f32x4 zero = {0.f, 0.f, 0.f, 0.f};
    f32x4 acc2a = zero, acc2b = zero;
#pragma unroll
    for (int ks = 0; ks < 4; ++ks) {
      const bf16x8 bw0 =
          *reinterpret_cast<const bf16x8*>(&wbf[131072 + n0 * 128 + ks * 32 + lq * 8]);
      const bf16x8 bw1 =
          *reinterpret_cast<const bf16x8*>(&wbf[131072 + n1 * 128 + ks * 32 + lq * 8]);
      acc2a = __builtin_amdgcn_mfma_f32_16x16x32_bf16(a2[ks], bw0, acc2a, 0, 0, 0);
      acc2b = __builtin_amdgcn_mfma_f32_16x16x32_bf16(a2[ks], bw1, acc2b, 0, 0, 0);
    }
    const float bya = b_out[n0];
    const float byb = b_out[n1];
#pragma unroll
    for (int i = 0; i < 4; ++i) {
      const size_t gr = (size_t)(row0 + rb2 + lq * 4 + i) * 128;
      out_y[gr + n0] = sigmoid_f(acc2a[i] + bya);
      out_y[gr + n1] = sigmoid_f(acc2b[i] + byb);
    }
  }
}

extern "C" void kernel_launch(void* const* d_in, const int* in_sizes, int n_in,
                              void* d_out, int out_size, void* d_ws, size_t ws_size,
                              hipStream_t stream) {
  const float* c_    = (const float*)d_in[0];
  const float* h_    = (const float*)d_in[1];
  const float* x     = (const float*)d_in[2];
  const float* w     = (const float*)d_in[3];
  const float* wi    = (const float*)d_in[4];
  const float* wf    = (const float*)d_in[5];
  const float* wo    = (const float*)d_in[6];
  const float* wout  = (const float*)d_in[7];
  const float* b     = (const float*)d_in[8];
  const float* bi    = (const float*)d_in[9];
  const float* bf_   = (const float*)d_in[10];
  const float* bo    = (const float*)d_in[11];
  const float* b_out = (const float*)d_in[12];

  unsigned short* wbf = (unsigned short*)d_ws;  // 147456 ushorts = 288 KiB
  float* out_c = (float*)d_out;
  float* out_h = out_c + (size_t)TB * 128;
  float* out_y = out_h + (size_t)TB * 128;

  hipLaunchKernelGGL(wconv_kernel, dim3(576), dim3(256), 0, stream,
                     w, wi, wf, wo, wout, wbf);
  hipLaunchKernelGGL(lstm_main, dim3(4096), dim3(256), 0, stream,
                     c_, h_, x, wbf, b, bi, bf_, bo, b_out, out_c, out_h, out_y);
}